// Round 2
// baseline (304.323 us; speedup 1.0000x reference)
//
#include <hip/hip_runtime.h>

// VQ-VAE codebook quantization, MI355X (gfx950)
// z: [32, 256, 32, 32] fp32 ; codebook: [1024, 256] fp32
// outputs (concat fp32): z_q [32,256,32,32] (8388608) | idx [32768] | loss [1]
//
// Correctness contract: idx must match numpy's fp32 argmin of
//   dist = fl( fl(znorm + enorm) - 2*dot ),  ties -> lowest index.
// The +znorm(~256) term quantizes dist to ulp ~1.5e-5; replicating that
// quantization (NOT dropping the constant term) is what makes ties match.

#define D_DIM   256
#define K_CODES 1024
#define HW      1024
#define MT      128     // positions per block
#define NT      256     // codes per N-chunk
#define BK      16      // d-chunk staged per barrier
#define THREADS 512

#define ZQ_OFF   0
#define IDX_OFF  8388608
#define LOSS_OFF 8421376

// As[256][128] + Es[16][256] + bestm[128] + znorm_s[128]
#define SMEM_FLOATS (D_DIM*MT + BK*NT + MT + MT)   // 32768+4096+128+128 = 37120
#define SMEM_BYTES  (SMEM_FLOATS * 4)              // 148480 B < 160 KiB/CU

extern __shared__ float smem[];

// ws: enorm[k] = fp32 sum of cb[k][d]^2 (own order; ~ulp(8e-5) agreement is enough)
__global__ void enorm_kernel(const float* __restrict__ cb, float* __restrict__ enorm) {
    int gt = blockIdx.x * blockDim.x + threadIdx.x;
    int k = gt >> 6;
    int lane = gt & 63;
    const float4* row = (const float4*)(cb + (size_t)k * D_DIM);
    float4 v = row[lane];
    float s = fmaf(v.x, v.x, fmaf(v.y, v.y, fmaf(v.z, v.z, v.w * v.w)));
    #pragma unroll
    for (int off = 32; off; off >>= 1) s += __shfl_xor(s, off);
    if (lane == 0) enorm[k] = s;
}

__global__ __launch_bounds__(THREADS, 2) void vq_kernel(
        const float* __restrict__ z, const float* __restrict__ cb,
        const float* __restrict__ enorm, float* __restrict__ out)
{
    float* As = smem;                                    // [256][128]
    float* Es = smem + D_DIM * MT;                       // [16][256] (also znorm scratch)
    int*   bestm   = (int*)(smem + D_DIM*MT + BK*NT);    // [128]
    float* znorm_s = (float*)(smem + D_DIM*MT + BK*NT + MT); // [128]

    const int t   = threadIdx.x;
    const int blk = blockIdx.x;          // 256 blocks = 1/CU
    const int b   = blk >> 3;
    const int p0  = (blk & 7) * MT;
    const float* zb = z + (size_t)b * D_DIM * HW;

    // ---- stage A^T [256][128] (z read from HBM once, coalesced float4) ----
    for (int i = t; i < D_DIM * MT / 4; i += THREADS) {
        int d = i >> 5, m4 = i & 31;
        *(float4*)(As + d * MT + m4 * 4) = *(const float4*)(zb + d * HW + p0 + m4 * 4);
    }
    __syncthreads();

    // ---- znorm[m] = fp64 sum of As[:,m]^2, rounded to fp32 ----
    // (fp64 vs numpy's pairwise-fp32 differs by <=1-2 ulp of ~256; that's a
    //  uniform exact-ulp shift per row -> argmin invariant.)
    {
        int m = t & (MT - 1), q = t >> 7;            // 4 quarters of d
        const float* col = As + m;
        double zp = 0.0;
        #pragma unroll 8
        for (int d = q * 64; d < q * 64 + 64; ++d) {
            double v = (double)col[d * MT];
            zp += v * v;
        }
        double* zscr = (double*)Es;                  // 512 doubles = 4 KB
        zscr[q * MT + m] = zp;
    }
    __syncthreads();
    if (t < MT) {
        double* zscr = (double*)Es;
        double s = (zscr[t] + zscr[MT + t]) + (zscr[2 * MT + t] + zscr[3 * MT + t]);
        znorm_s[t] = (float)s;
    }
    __syncthreads();

    const int tx = t & 31, ty = t >> 5;
    const int m_base = ty * 8;           // 16 ty-groups x 8 = 128 positions
    const int kx = tx * 8;               // 32 tx x 8 = 256 codes per chunk

    float znf[8];
    #pragma unroll
    for (int i = 0; i < 8; ++i) znf[i] = znorm_s[m_base + i];

    float bestv[8]; int besti[8];
    #pragma unroll
    for (int i = 0; i < 8; ++i) { bestv[i] = 3.4e38f; besti[i] = 0; }

    for (int c = 0; c < 4; ++c) {
        const int k0 = c * NT;
        float acc[8][8];
        #pragma unroll
        for (int i = 0; i < 8; ++i)
            #pragma unroll
            for (int j = 0; j < 8; ++j) acc[i][j] = 0.f;

        for (int dk = 0; dk < D_DIM; dk += BK) {
            __syncthreads();
            // stage E tile: Es[dd][k] = cb[k0+k][dk+dd] (codebook L2-resident)
            for (int i = t; i < BK * NT / 4; i += THREADS) {
                int kk = i >> 2, d4 = i & 3;
                float4 v = *(const float4*)(cb + (size_t)(k0 + kk) * D_DIM + dk + d4 * 4);
                Es[(d4 * 4 + 0) * NT + kk] = v.x;
                Es[(d4 * 4 + 1) * NT + kk] = v.y;
                Es[(d4 * 4 + 2) * NT + kk] = v.z;
                Es[(d4 * 4 + 3) * NT + kk] = v.w;
            }
            __syncthreads();
            #pragma unroll
            for (int dd = 0; dd < BK; ++dd) {
                float a[8], e[8];
                *(float4*)(a)     = *(const float4*)(As + (dk + dd) * MT + m_base);
                *(float4*)(a + 4) = *(const float4*)(As + (dk + dd) * MT + m_base + 4);
                *(float4*)(e)     = *(const float4*)(Es + dd * NT + kx);
                *(float4*)(e + 4) = *(const float4*)(Es + dd * NT + kx + 4);
                #pragma unroll
                for (int i = 0; i < 8; ++i)
                    #pragma unroll
                    for (int j = 0; j < 8; ++j)
                        acc[i][j] = fmaf(a[i], e[j], acc[i][j]);
            }
        }
        // chunk epilogue: dist = fl( fl(znorm + enorm_k) - 2*dot ), np-style
        #pragma unroll
        for (int j = 0; j < 8; ++j) {
            float bn = enorm[k0 + kx + j];
            int kidx = k0 + kx + j;
            #pragma unroll
            for (int i = 0; i < 8; ++i) {
                float A   = znf[i] + bn;               // rounds at ~256 scale
                float val = A - 2.0f * acc[i][j];      // 2*acc exact; single rounding
                if (val < bestv[i] || (val == bestv[i] && kidx < besti[i])) {
                    bestv[i] = val; besti[i] = kidx;
                }
            }
        }
    }

    // ---- argmin reduce across tx (32 lanes = half-wave), lowest index on ties ----
    #pragma unroll
    for (int i = 0; i < 8; ++i) {
        float v = bestv[i]; int ix = besti[i];
        #pragma unroll
        for (int off = 16; off; off >>= 1) {
            float ov = __shfl_xor(v, off);
            int   oi = __shfl_xor(ix, off);
            if (ov < v || (ov == v && oi < ix)) { v = ov; ix = oi; }
        }
        if (tx == 0) {
            bestm[m_base + i] = ix;
            out[IDX_OFF + (size_t)blk * MT + m_base + i] = (float)ix;
        }
    }
    __syncthreads();

    // ---- epilogue: gather codebook rows (L2), write z_q coalesced, loss ----
    float lsum = 0.f;
    const size_t zq_base = (size_t)b * D_DIM * HW + p0;
    for (int i2 = t; i2 < D_DIM * MT / 4; i2 += THREADS) {
        int p = i2 & (MT - 1), d4 = i2 >> 7;
        int idx = bestm[p];
        float4 cv = *(const float4*)(cb + (size_t)idx * D_DIM + d4 * 4);
        float z0 = As[(d4 * 4 + 0) * MT + p];
        float z1 = As[(d4 * 4 + 1) * MT + p];
        float z2 = As[(d4 * 4 + 2) * MT + p];
        float z3 = As[(d4 * 4 + 3) * MT + p];
        float e0 = cv.x - z0, e1 = cv.y - z1, e2 = cv.z - z2, e3 = cv.w - z3;
        lsum = fmaf(e0, e0, lsum); lsum = fmaf(e1, e1, lsum);
        lsum = fmaf(e2, e2, lsum); lsum = fmaf(e3, e3, lsum);
        out[zq_base + (size_t)(d4 * 4 + 0) * HW + p] = cv.x;
        out[zq_base + (size_t)(d4 * 4 + 1) * HW + p] = cv.y;
        out[zq_base + (size_t)(d4 * 4 + 2) * HW + p] = cv.z;
        out[zq_base + (size_t)(d4 * 4 + 3) * HW + p] = cv.w;
    }
    #pragma unroll
    for (int off = 32; off; off >>= 1) lsum += __shfl_xor(lsum, off);
    __syncthreads();
    if ((t & 63) == 0) Es[t >> 6] = lsum;
    __syncthreads();
    if (t == 0) {
        float s = 0.f;
        #pragma unroll
        for (int w = 0; w < 8; ++w) s += Es[w];
        atomicAdd(out + LOSS_OFF, s * (1.25f / 8388608.f));
    }
}

extern "C" void kernel_launch(void* const* d_in, const int* in_sizes, int n_in,
                              void* d_out, int out_size, void* d_ws, size_t ws_size,
                              hipStream_t stream) {
    const float* z  = (const float*)d_in[0];
    const float* cb = (const float*)d_in[1];
    float* out = (float*)d_out;
    float* enorm = (float*)d_ws;

    hipMemsetAsync(out + LOSS_OFF, 0, sizeof(float), stream);

    enorm_kernel<<<256, 256, 0, stream>>>(cb, enorm);

    hipFuncSetAttribute((const void*)vq_kernel,
                        hipFuncAttributeMaxDynamicSharedMemorySize, SMEM_BYTES);
    vq_kernel<<<256, THREADS, SMEM_BYTES, stream>>>(z, cb, enorm, out);
}